// Round 12
// baseline (91.191 us; speedup 1.0000x reference)
//
#include <hip/hip_runtime.h>

// SNN excitatory layer only (inhibitory layer never affects the returned
// spikes — the scan discards its carry).
//
// R11 = R10 (2 neurons x 1024 cols per wave; best measured) with the
// per-step __syncthreads replaced by an LDS-ONLY barrier:
//     s_waitcnt lgkmcnt(0); s_barrier
// __syncthreads() emits s_waitcnt vmcnt(0) lgkmcnt(0) before s_barrier,
// force-draining the wave-private x/tq prefetch loads every step — that
// drain is the recurring ~300-600 cy/step stall R3-R10 kept hitting from
// different angles. Only the 16-float LDS partial exchange needs barrier
// ordering, and lgkmcnt(0) covers it. Global prefetches now stay in
// flight across step boundaries (counted vmcnt at the use).

constexpr int T_STEPS = 128;
constexpr int N_IN    = 2048;
constexpr int N_EXC   = 2048;
constexpr int HALF    = 1024;

// t_pre[t][j]: trace AFTER the step-t update (what stdp_step's dw uses).
__global__ __launch_bounds__(256)
void tp_precompute_kernel(const float* __restrict__ x, float* __restrict__ tp_ws) {
    const int j = blockIdx.x * blockDim.x + threadIdx.x;
    float tp = 0.f;
    #pragma unroll 16
    for (int t = 0; t < T_STEPS; ++t) {
        tp = fmaf(0.05f, x[t * N_IN + j] - tp, tp);
        tp_ws[t * N_IN + j] = tp;
    }
}

template <int CTRL, int RM>
__device__ __forceinline__ float dpp_add(float x) {
    int t = __builtin_amdgcn_update_dpp(0, __builtin_bit_cast(int, x),
                                        CTRL, RM, 0xF, true);
    return x + __builtin_bit_cast(float, t);
}

// After this chain, lane 63 holds the 64-lane sum (no readlane).
__device__ __forceinline__ float wave_sum64_to_lane63(float x) {
    x = dpp_add<0x111, 0xF>(x);   // row_shr:1
    x = dpp_add<0x112, 0xF>(x);   // row_shr:2
    x = dpp_add<0x114, 0xF>(x);   // row_shr:4
    x = dpp_add<0x118, 0xF>(x);   // row_shr:8
    x = dpp_add<0x142, 0xA>(x);   // row_bcast:15 -> rows 1,3
    x = dpp_add<0x143, 0xC>(x);   // row_bcast:31 -> rows 2,3
    return x;
}

__device__ __forceinline__ float clamp01(float x) {
    return __builtin_amdgcn_fmed3f(x, 0.f, 1.f);   // folds to clamp bit
}

// Workgroup barrier that orders LDS ops only — does NOT drain vmcnt.
__device__ __forceinline__ void barrier_lds() {
    asm volatile("s_waitcnt lgkmcnt(0)" ::: "memory");
    __builtin_amdgcn_s_barrier();
    asm volatile("" ::: "memory");   // no hoisting of LDS reads above barrier
}

__global__ __launch_bounds__(256, 2)
void snn_exc_kernel(const float* __restrict__ x,     // [T, N_IN]
                    const float* __restrict__ w0,    // [N_EXC, N_IN]
                    const float* __restrict__ tp_ws, // [T, N_IN]
                    float* __restrict__ out)         // [T, N_EXC]
{
    // part[buf][pair][half][neuron]: lane63 of wave (p,h) writes {A,B} as b64;
    // wave (p,*) reads its 4 floats {A0,B0,A1,B1} as one b128.
    __shared__ float part[2][2][2][2];               // 64 B

    const int tid  = threadIdx.x;
    const int lane = tid & 63;
    const int wid  = tid >> 6;
    const int p    = wid >> 1;          // neuron pair within block
    const int h    = wid & 1;           // column half
    const int rA   = blockIdx.x * 4 + 2 * p;   // rows rA, rA+1

    // lane l owns cols j = h*1024 + m*256 + l*4 + {0..3}, m = 0..3
    float wA[16], wB[16];
    {
        const float4* ra = reinterpret_cast<const float4*>(w0 + (size_t)rA * N_IN + h * HALF);
        const float4* rb = reinterpret_cast<const float4*>(w0 + (size_t)(rA + 1) * N_IN + h * HALF);
        #pragma unroll
        for (int m = 0; m < 4; ++m) {
            float4 a = ra[m * 64 + lane];
            float4 b = rb[m * 64 + lane];
            wA[4*m+0] = a.x; wA[4*m+1] = a.y; wA[4*m+2] = a.z; wA[4*m+3] = a.w;
            wB[4*m+0] = b.x; wB[4*m+1] = b.y; wB[4*m+2] = b.z; wB[4*m+3] = b.w;
        }
    }

    const float4* xsl = reinterpret_cast<const float4*>(x + h * HALF) + lane;
    const float4* tps = reinterpret_cast<const float4*>(tp_ws + h * HALF) + lane;

    if (tid < 16) reinterpret_cast<float*>(part)[tid] = 0.f;

    float4 xa[4], xb[4];
    #pragma unroll
    for (int m = 0; m < 4; ++m) xa[m] = xsl[m * 64];   // x_0 slice
    barrier_lds();                                     // publishes zeroed part

    float vA = 0.f, synA = 0.f, rhoA = 0.f, tpostA = 0.f;
    float vB = 0.f, synB = 0.f, rhoB = 0.f, tpostB = 0.f;

    auto step = [&](int t, const float4 (&xc)[4], float4 (&xn)[4]) {
        // ---- (1) prefetch x slice of row t+1 (stays in flight across the
        //          step-end barrier; waited by counted vmcnt at next use) ----
        int tn = t + 1; if (tn > T_STEPS - 1) tn = T_STEPS - 1;
        const float4* xp = xsl + (size_t)tn * (N_IN / 4);
        #pragma unroll
        for (int m = 0; m < 4; ++m) xn[m] = xp[m * 64];

        // ---- (2) read step-(t-1) partials {A0,B0,A1,B1}; complete syn ----
        const float4 pp = *reinterpret_cast<const float4*>(&part[t & 1][p][0][0]);
        synA = fmaf(0.8f, synA, pp.x + pp.z);
        synB = fmaf(0.8f, synB, pp.y + pp.w);

        // ---- (3) LIF both neurons (spike known before the dot) ----
        const float vdA = fmaf(0.1f, synA - vA, vA);
        const bool  rfA = (rhoA > 0.f);
        const bool  kA  = (vdA > 1.0f) && !rfA;
        vA     = (kA || rfA) ? 0.f : vdA;
        rhoA   = kA ? 5.0f : fmaxf(rhoA - 1.0f, 0.f);
        const float zA = kA ? 1.f : 0.f;
        tpostA = fmaf(0.05f, zA - tpostA, tpostA);
        const float c2A = 1e-3f * tpostA;

        const float vdB = fmaf(0.1f, synB - vB, vB);
        const bool  rfB = (rhoB > 0.f);
        const bool  kB  = (vdB > 1.0f) && !rfB;
        vB     = (kB || rfB) ? 0.f : vdB;
        rhoB   = kB ? 5.0f : fmaxf(rhoB - 1.0f, 0.f);
        const float zB = kB ? 1.f : 0.f;
        tpostB = fmaf(0.05f, zB - tpostB, tpostB);
        const float c2B = 1e-3f * tpostB;

        if (h == 0 && lane == 0) {
            float2 zz; zz.x = zA; zz.y = zB;
            *reinterpret_cast<float2*>(out + (size_t)t * N_EXC + rA) = zz;
        }

        const int sA = __builtin_amdgcn_readfirstlane((int)kA);
        const int sB = __builtin_amdgcn_readfirstlane((int)kB);

        // ---- (4) t_pre slice, only if either neuron spiked ----
        float4 tq[4];
        if (sA | sB) {
            const float4* tp4 = tps + (size_t)t * (N_IN / 4);
            #pragma unroll
            for (int m = 0; m < 4; ++m) tq[m] = tp4[m * 64];
        }

        // ---- (5) two dots over PRE-update w (x reused from registers) ----
        float a0 = 0.f, a1 = 0.f, a2 = 0.f, a3 = 0.f;
        float b0 = 0.f, b1 = 0.f, b2 = 0.f, b3 = 0.f;
        #pragma unroll
        for (int m = 0; m < 4; ++m) {
            a0 = fmaf(xc[m].x, wA[4*m+0], a0);
            b0 = fmaf(xc[m].x, wB[4*m+0], b0);
            a1 = fmaf(xc[m].y, wA[4*m+1], a1);
            b1 = fmaf(xc[m].y, wB[4*m+1], b1);
            a2 = fmaf(xc[m].z, wA[4*m+2], a2);
            b2 = fmaf(xc[m].z, wB[4*m+2], b2);
            a3 = fmaf(xc[m].w, wA[4*m+3], a3);
            b3 = fmaf(xc[m].w, wB[4*m+3], b3);
        }

        // ---- (6) reduce to lane 63; publish both partials as one b64 ----
        const float sAr = wave_sum64_to_lane63((a0 + a1) + (a2 + a3));
        const float sBr = wave_sum64_to_lane63((b0 + b1) + (b2 + b3));
        if (lane == 63) {
            float2 pw; pw.x = sAr; pw.y = sBr;
            *reinterpret_cast<float2*>(&part[(t + 1) & 1][p][h][0]) = pw;
        }

        // ---- (7) STDP updates (wave-uniform branches) ----
        if (sA) {
            #pragma unroll
            for (int m = 0; m < 4; ++m) {
                wA[4*m+0] = clamp01(fmaf(1e-3f, tq[m].x, fmaf(-c2A, xc[m].x, wA[4*m+0])));
                wA[4*m+1] = clamp01(fmaf(1e-3f, tq[m].y, fmaf(-c2A, xc[m].y, wA[4*m+1])));
                wA[4*m+2] = clamp01(fmaf(1e-3f, tq[m].z, fmaf(-c2A, xc[m].z, wA[4*m+2])));
                wA[4*m+3] = clamp01(fmaf(1e-3f, tq[m].w, fmaf(-c2A, xc[m].w, wA[4*m+3])));
            }
        } else {
            #pragma unroll
            for (int m = 0; m < 4; ++m) {
                wA[4*m+0] = clamp01(fmaf(-c2A, xc[m].x, wA[4*m+0]));
                wA[4*m+1] = clamp01(fmaf(-c2A, xc[m].y, wA[4*m+1]));
                wA[4*m+2] = clamp01(fmaf(-c2A, xc[m].z, wA[4*m+2]));
                wA[4*m+3] = clamp01(fmaf(-c2A, xc[m].w, wA[4*m+3]));
            }
        }
        if (sB) {
            #pragma unroll
            for (int m = 0; m < 4; ++m) {
                wB[4*m+0] = clamp01(fmaf(1e-3f, tq[m].x, fmaf(-c2B, xc[m].x, wB[4*m+0])));
                wB[4*m+1] = clamp01(fmaf(1e-3f, tq[m].y, fmaf(-c2B, xc[m].y, wB[4*m+1])));
                wB[4*m+2] = clamp01(fmaf(1e-3f, tq[m].z, fmaf(-c2B, xc[m].z, wB[4*m+2])));
                wB[4*m+3] = clamp01(fmaf(1e-3f, tq[m].w, fmaf(-c2B, xc[m].w, wB[4*m+3])));
            }
        } else {
            #pragma unroll
            for (int m = 0; m < 4; ++m) {
                wB[4*m+0] = clamp01(fmaf(-c2B, xc[m].x, wB[4*m+0]));
                wB[4*m+1] = clamp01(fmaf(-c2B, xc[m].y, wB[4*m+1]));
                wB[4*m+2] = clamp01(fmaf(-c2B, xc[m].z, wB[4*m+2]));
                wB[4*m+3] = clamp01(fmaf(-c2B, xc[m].w, wB[4*m+3]));
            }
        }

        // ---- (8) LDS-only barrier: publishes part[(t+1)&1] for step t+1;
        //          x/tq prefetches stay in flight ----
        barrier_lds();
    };

    for (int t = 0; t < T_STEPS; t += 2) {
        step(t,     xa, xb);
        step(t + 1, xb, xa);
    }
}

extern "C" void kernel_launch(void* const* d_in, const int* in_sizes, int n_in,
                              void* d_out, int out_size, void* d_ws, size_t ws_size,
                              hipStream_t stream) {
    const float* x  = (const float*)d_in[0];   // exc_currents [128, 2048] f32
    const float* w0 = (const float*)d_in[1];   // w_exc [2048, 2048] f32
    // d_in[2] (w_inh) unused: inhibitory layer does not affect the output
    float* out = (float*)d_out;                // spikes [128, 2048] f32

    float* tp_ws = (float*)d_ws;               // 1 MiB, ws_size is ample
    tp_precompute_kernel<<<N_IN / 256, 256, 0, stream>>>(x, tp_ws);

    dim3 grid(N_EXC / 4);                      // 512 blocks, 2 blocks/CU
    dim3 block(256);                           // 4 waves = 2 pairs x 2 halves
    snn_exc_kernel<<<grid, block, 0, stream>>>(x, w0, tp_ws, out);
}

// Round 13
// 88.400 us; speedup vs baseline: 1.0316x; 1.0316x over previous
//
#include <hip/hip_runtime.h>

// SNN excitatory layer only (inhibitory layer never affects the returned
// spikes — the scan discards its carry).
//
// R12 = R10/R11 (2 neurons x 1024 cols per wave) + final latency/issue combo:
//  - prefetch distance 2: x(t+2) issued at step END into the buffer just
//    consumed (same registers, ~2 steps of slack instead of <=1), combined
//    with the LDS-only barrier (no vmcnt drain) so the slack is real.
//  - dot product via float2 __builtin_elementwise_fma -> v_pk_fma_f32:
//    16 packed fma replace 32 scalar fma, bit-identical grouping.
//  - LIF / STDP / reduce / exchange identical to R10 -> spike-exact.

constexpr int T_STEPS = 128;
constexpr int N_IN    = 2048;
constexpr int N_EXC   = 2048;
constexpr int HALF    = 1024;

typedef float f2 __attribute__((ext_vector_type(2)));

// t_pre[t][j]: trace AFTER the step-t update (what stdp_step's dw uses).
__global__ __launch_bounds__(256)
void tp_precompute_kernel(const float* __restrict__ x, float* __restrict__ tp_ws) {
    const int j = blockIdx.x * blockDim.x + threadIdx.x;
    float tp = 0.f;
    #pragma unroll 16
    for (int t = 0; t < T_STEPS; ++t) {
        tp = fmaf(0.05f, x[t * N_IN + j] - tp, tp);
        tp_ws[t * N_IN + j] = tp;
    }
}

template <int CTRL, int RM>
__device__ __forceinline__ float dpp_add(float x) {
    int t = __builtin_amdgcn_update_dpp(0, __builtin_bit_cast(int, x),
                                        CTRL, RM, 0xF, true);
    return x + __builtin_bit_cast(float, t);
}

// After this chain, lane 63 holds the 64-lane sum (no readlane).
__device__ __forceinline__ float wave_sum64_to_lane63(float x) {
    x = dpp_add<0x111, 0xF>(x);   // row_shr:1
    x = dpp_add<0x112, 0xF>(x);   // row_shr:2
    x = dpp_add<0x114, 0xF>(x);   // row_shr:4
    x = dpp_add<0x118, 0xF>(x);   // row_shr:8
    x = dpp_add<0x142, 0xA>(x);   // row_bcast:15 -> rows 1,3
    x = dpp_add<0x143, 0xC>(x);   // row_bcast:31 -> rows 2,3
    return x;
}

__device__ __forceinline__ float clamp01(float x) {
    return __builtin_amdgcn_fmed3f(x, 0.f, 1.f);   // folds to clamp bit
}

// Workgroup barrier that orders LDS ops only — does NOT drain vmcnt.
__device__ __forceinline__ void barrier_lds() {
    asm volatile("s_waitcnt lgkmcnt(0)" ::: "memory");
    __builtin_amdgcn_s_barrier();
    asm volatile("" ::: "memory");
}

__global__ __launch_bounds__(256, 2)
void snn_exc_kernel(const float* __restrict__ x,     // [T, N_IN]
                    const float* __restrict__ w0,    // [N_EXC, N_IN]
                    const float* __restrict__ tp_ws, // [T, N_IN]
                    float* __restrict__ out)         // [T, N_EXC]
{
    // part[buf][pair][half][neuron]: lane63 of wave (p,h) writes {A,B} as b64;
    // wave (p,*) reads its 4 floats {A0,B0,A1,B1} as one b128.
    __shared__ float part[2][2][2][2];               // 64 B

    const int tid  = threadIdx.x;
    const int lane = tid & 63;
    const int wid  = tid >> 6;
    const int p    = wid >> 1;          // neuron pair within block
    const int h    = wid & 1;           // column half
    const int rA   = blockIdx.x * 4 + 2 * p;   // rows rA, rA+1

    // lane l owns cols j = h*1024 + m*256 + l*4 + {0..3}, m = 0..3
    float wA[16], wB[16];
    {
        const float4* ra = reinterpret_cast<const float4*>(w0 + (size_t)rA * N_IN + h * HALF);
        const float4* rb = reinterpret_cast<const float4*>(w0 + (size_t)(rA + 1) * N_IN + h * HALF);
        #pragma unroll
        for (int m = 0; m < 4; ++m) {
            float4 a = ra[m * 64 + lane];
            float4 b = rb[m * 64 + lane];
            wA[4*m+0] = a.x; wA[4*m+1] = a.y; wA[4*m+2] = a.z; wA[4*m+3] = a.w;
            wB[4*m+0] = b.x; wB[4*m+1] = b.y; wB[4*m+2] = b.z; wB[4*m+3] = b.w;
        }
    }

    const float4* xsl = reinterpret_cast<const float4*>(x + h * HALF) + lane;
    const float4* tps = reinterpret_cast<const float4*>(tp_ws + h * HALF) + lane;

    if (tid < 16) reinterpret_cast<float*>(part)[tid] = 0.f;

    float4 xa[4], xb[4];
    #pragma unroll
    for (int m = 0; m < 4; ++m) xa[m] = xsl[m * 64];                    // x_0
    #pragma unroll
    for (int m = 0; m < 4; ++m) xb[m] = xsl[(N_IN / 4) + m * 64];       // x_1
    barrier_lds();                                   // publishes zeroed part

    float vA = 0.f, synA = 0.f, rhoA = 0.f, tpostA = 0.f;
    float vB = 0.f, synB = 0.f, rhoB = 0.f, tpostB = 0.f;

    auto step = [&](int t, float4 (&xc)[4]) {
        // ---- (1) read step-(t-1) partials {A0,B0,A1,B1}; complete syn ----
        const float4 pp = *reinterpret_cast<const float4*>(&part[t & 1][p][0][0]);
        synA = fmaf(0.8f, synA, pp.x + pp.z);
        synB = fmaf(0.8f, synB, pp.y + pp.w);

        // ---- (2) LIF both neurons (spike known before the dot) ----
        const float vdA = fmaf(0.1f, synA - vA, vA);
        const bool  rfA = (rhoA > 0.f);
        const bool  kA  = (vdA > 1.0f) && !rfA;
        vA     = (kA || rfA) ? 0.f : vdA;
        rhoA   = kA ? 5.0f : fmaxf(rhoA - 1.0f, 0.f);
        const float zA = kA ? 1.f : 0.f;
        tpostA = fmaf(0.05f, zA - tpostA, tpostA);
        const float c2A = 1e-3f * tpostA;

        const float vdB = fmaf(0.1f, synB - vB, vB);
        const bool  rfB = (rhoB > 0.f);
        const bool  kB  = (vdB > 1.0f) && !rfB;
        vB     = (kB || rfB) ? 0.f : vdB;
        rhoB   = kB ? 5.0f : fmaxf(rhoB - 1.0f, 0.f);
        const float zB = kB ? 1.f : 0.f;
        tpostB = fmaf(0.05f, zB - tpostB, tpostB);
        const float c2B = 1e-3f * tpostB;

        if (h == 0 && lane == 0) {
            float2 zz; zz.x = zA; zz.y = zB;
            *reinterpret_cast<float2*>(out + (size_t)t * N_EXC + rA) = zz;
        }

        const int sA = __builtin_amdgcn_readfirstlane((int)kA);
        const int sB = __builtin_amdgcn_readfirstlane((int)kB);

        // ---- (3) t_pre slice, only if either neuron spiked ----
        float4 tq[4];
        if (sA | sB) {
            const float4* tp4 = tps + (size_t)t * (N_IN / 4);
            #pragma unroll
            for (int m = 0; m < 4; ++m) tq[m] = tp4[m * 64];
        }

        // ---- (4) two dots over PRE-update w, packed fp32 (v_pk_fma_f32);
        //          grouping identical to (a0+a1)+(a2+a3) -> bit-exact ----
        const f2* xc2 = reinterpret_cast<const f2*>(&xc[0]);
        const f2* wA2 = reinterpret_cast<const f2*>(wA);
        const f2* wB2 = reinterpret_cast<const f2*>(wB);
        f2 aL = {0.f, 0.f}, aH = {0.f, 0.f};
        f2 bL = {0.f, 0.f}, bH = {0.f, 0.f};
        #pragma unroll
        for (int m = 0; m < 4; ++m) {
            aL = __builtin_elementwise_fma(xc2[2*m],   wA2[2*m],   aL);
            bL = __builtin_elementwise_fma(xc2[2*m],   wB2[2*m],   bL);
            aH = __builtin_elementwise_fma(xc2[2*m+1], wA2[2*m+1], aH);
            bH = __builtin_elementwise_fma(xc2[2*m+1], wB2[2*m+1], bH);
        }

        // ---- (5) reduce to lane 63; publish both partials as one b64 ----
        const float sAr = wave_sum64_to_lane63((aL.x + aL.y) + (aH.x + aH.y));
        const float sBr = wave_sum64_to_lane63((bL.x + bL.y) + (bH.x + bH.y));
        if (lane == 63) {
            float2 pw; pw.x = sAr; pw.y = sBr;
            *reinterpret_cast<float2*>(&part[(t + 1) & 1][p][h][0]) = pw;
        }

        // ---- (6) STDP updates (wave-uniform branches) ----
        if (sA) {
            #pragma unroll
            for (int m = 0; m < 4; ++m) {
                wA[4*m+0] = clamp01(fmaf(1e-3f, tq[m].x, fmaf(-c2A, xc[m].x, wA[4*m+0])));
                wA[4*m+1] = clamp01(fmaf(1e-3f, tq[m].y, fmaf(-c2A, xc[m].y, wA[4*m+1])));
                wA[4*m+2] = clamp01(fmaf(1e-3f, tq[m].z, fmaf(-c2A, xc[m].z, wA[4*m+2])));
                wA[4*m+3] = clamp01(fmaf(1e-3f, tq[m].w, fmaf(-c2A, xc[m].w, wA[4*m+3])));
            }
        } else {
            #pragma unroll
            for (int m = 0; m < 4; ++m) {
                wA[4*m+0] = clamp01(fmaf(-c2A, xc[m].x, wA[4*m+0]));
                wA[4*m+1] = clamp01(fmaf(-c2A, xc[m].y, wA[4*m+1]));
                wA[4*m+2] = clamp01(fmaf(-c2A, xc[m].z, wA[4*m+2]));
                wA[4*m+3] = clamp01(fmaf(-c2A, xc[m].w, wA[4*m+3]));
            }
        }
        if (sB) {
            #pragma unroll
            for (int m = 0; m < 4; ++m) {
                wB[4*m+0] = clamp01(fmaf(1e-3f, tq[m].x, fmaf(-c2B, xc[m].x, wB[4*m+0])));
                wB[4*m+1] = clamp01(fmaf(1e-3f, tq[m].y, fmaf(-c2B, xc[m].y, wB[4*m+1])));
                wB[4*m+2] = clamp01(fmaf(1e-3f, tq[m].z, fmaf(-c2B, xc[m].z, wB[4*m+2])));
                wB[4*m+3] = clamp01(fmaf(1e-3f, tq[m].w, fmaf(-c2B, xc[m].w, wB[4*m+3])));
            }
        } else {
            #pragma unroll
            for (int m = 0; m < 4; ++m) {
                wB[4*m+0] = clamp01(fmaf(-c2B, xc[m].x, wB[4*m+0]));
                wB[4*m+1] = clamp01(fmaf(-c2B, xc[m].y, wB[4*m+1]));
                wB[4*m+2] = clamp01(fmaf(-c2B, xc[m].z, wB[4*m+2]));
                wB[4*m+3] = clamp01(fmaf(-c2B, xc[m].w, wB[4*m+3]));
            }
        }

        // ---- (7) LDS-only barrier (no vmcnt drain) ----
        barrier_lds();

        // ---- (8) prefetch x(t+2) into the buffer just freed: ~2 full
        //          steps of slack; in-flight across both barriers ----
        int tn = t + 2; if (tn > T_STEPS - 1) tn = T_STEPS - 1;
        const float4* xp = xsl + (size_t)tn * (N_IN / 4);
        #pragma unroll
        for (int m = 0; m < 4; ++m) xc[m] = xp[m * 64];
    };

    for (int t = 0; t < T_STEPS; t += 2) {
        step(t,     xa);
        step(t + 1, xb);
    }
}

extern "C" void kernel_launch(void* const* d_in, const int* in_sizes, int n_in,
                              void* d_out, int out_size, void* d_ws, size_t ws_size,
                              hipStream_t stream) {
    const float* x  = (const float*)d_in[0];   // exc_currents [128, 2048] f32
    const float* w0 = (const float*)d_in[1];   // w_exc [2048, 2048] f32
    // d_in[2] (w_inh) unused: inhibitory layer does not affect the output
    float* out = (float*)d_out;                // spikes [128, 2048] f32

    float* tp_ws = (float*)d_ws;               // 1 MiB, ws_size is ample
    tp_precompute_kernel<<<N_IN / 256, 256, 0, stream>>>(x, tp_ws);

    dim3 grid(N_EXC / 4);                      // 512 blocks, 2 blocks/CU
    dim3 block(256);                           // 4 waves = 2 pairs x 2 halves
    snn_exc_kernel<<<grid, block, 0, stream>>>(x, w0, tp_ws, out);
}